// Round 1
// baseline (357.975 us; speedup 1.0000x reference)
//
#include <hip/hip_runtime.h>
#include <stdint.h>
#include <math.h>

// Problem constants (SwitchFeedForwardTail): x (2,1024,768) f32, Ws (768,9),
// W1 (9,768,3072), W2 (9,3072,768). Output only needs expert-0 ("common") and
// expert routes[t] ("sel") per token -> <= 2 FFN evals/token instead of 9.
#define T_TOK 2048
#define DM 768
#define DF 3072
#define NE 9

typedef unsigned short ushort_t;
typedef __attribute__((ext_vector_type(8))) __bf16 bf16x8;
typedef __attribute__((ext_vector_type(4))) float f32x4;

__device__ __forceinline__ unsigned short f2bf(float f) {
  union { float f; uint32_t u; } v; v.f = f;
  uint32_t u = v.u;
  u = u + 0x7fffu + ((u >> 16) & 1u);   // round-to-nearest-even
  return (unsigned short)(u >> 16);
}

__device__ __forceinline__ void gl_lds16(const void* g, void* l) {
  __builtin_amdgcn_global_load_lds(
      (const __attribute__((address_space(1))) unsigned int*)g,
      (__attribute__((address_space(3))) unsigned int*)l, 16, 0, 0);
}

// ---------------- routing: logits = x @ Ws + bs, softmax, p/argmax ----------
// one wave per token; also emits x in bf16 (fused conversion).
__global__ __launch_bounds__(256) void route_kernel(
    const float* __restrict__ x, const float* __restrict__ Ws,
    const float* __restrict__ bs, ushort_t* __restrict__ xb,
    float* __restrict__ p, int* __restrict__ routes,
    int* __restrict__ counts, int* __restrict__ lists) {
  const int wave = threadIdx.x >> 6, lane = threadIdx.x & 63;
  const int t = blockIdx.x * 4 + wave;
  const float* xr = x + (size_t)t * DM;
  const int d0 = lane * 12;                      // 768 = 64 lanes * 12
  float xv[12];
#pragma unroll
  for (int i = 0; i < 12; ++i) xv[i] = xr[d0 + i];
#pragma unroll
  for (int i = 0; i < 12; ++i) xb[(size_t)t * DM + d0 + i] = f2bf(xv[i]);
  float acc[NE];
#pragma unroll
  for (int e = 0; e < NE; ++e) acc[e] = 0.f;
#pragma unroll
  for (int i = 0; i < 12; ++i) {
    const float* wr = Ws + (size_t)(d0 + i) * NE;
#pragma unroll
    for (int e = 0; e < NE; ++e) acc[e] += xv[i] * wr[e];
  }
#pragma unroll
  for (int off = 32; off >= 1; off >>= 1)
#pragma unroll
    for (int e = 0; e < NE; ++e) acc[e] += __shfl_xor(acc[e], off);
  if (lane == 0) {
    float m = -1e30f; int am = 0;
#pragma unroll
    for (int e = 0; e < NE; ++e) {
      float l = acc[e] + bs[e];
      acc[e] = l;
      if (l > m) { m = l; am = e; }              // strict > : first max, matches argmax
    }
    float s = 0.f;
#pragma unroll
    for (int e = 0; e < NE; ++e) s += expf(acc[e] - m);
    p[t] = 1.0f / s;                             // prob of the max logit
    routes[t] = am;
    if (am != 0) {
      int pos = atomicAdd(&counts[am], 1);
      lists[(am - 1) * T_TOK + pos] = t;
    }
  }
}

// ------------- transpose + f32->bf16 convert: in (E,rows,cols) -> out (E,cols,rows)
__global__ __launch_bounds__(256) void transpose_conv(
    const float* __restrict__ in, ushort_t* __restrict__ out,
    int rows, int cols) {
  __shared__ float tile[32][33];
  const int e = blockIdx.z;
  const float* src = in + (size_t)e * rows * cols;
  ushort_t* dst = out + (size_t)e * rows * cols;
  const int c0 = blockIdx.x * 32, r0 = blockIdx.y * 32;
  const int tx = threadIdx.x & 31, ty = threadIdx.x >> 5;   // 32x8
#pragma unroll
  for (int i = 0; i < 32; i += 8)
    tile[ty + i][tx] = src[(size_t)(r0 + ty + i) * cols + (c0 + tx)];
  __syncthreads();
#pragma unroll
  for (int i = 0; i < 32; i += 8)
    dst[(size_t)(c0 + ty + i) * rows + (r0 + tx)] = f2bf(tile[tx][ty + i]);
}

// ------------- grouped gather-GEMM, 128x128 tile, BK=64, 4 waves ------------
// A: rows gathered by token list (expert 0 = identity over all tokens).
// B: (NE, N, K) bf16, K-contiguous (pre-transposed).
// PASS1: D = gelu(A@B + bias) -> bf16 (by token). else: D = A@B + bias -> f32.
template <int K, int N, bool PASS1>
__global__ __launch_bounds__(256) void ffn_gemm(
    const ushort_t* __restrict__ Asrc0, const ushort_t* __restrict__ AsrcS,
    const ushort_t* __restrict__ Btb, const float* __restrict__ bias,
    const int* __restrict__ counts, const int* __restrict__ lists,
    ushort_t* __restrict__ D0b, ushort_t* __restrict__ DSb,
    float* __restrict__ D0f, float* __restrict__ DSf) {
  const int e = blockIdx.z;
  const int cnt = (e == 0) ? T_TOK : counts[e];
  const int m0 = blockIdx.y * 128;
  if (m0 >= cnt) return;
  const int n0 = blockIdx.x * 128;
  const int* list = lists + (e - 1) * T_TOK;     // deref only when e>0
  const ushort_t* Asrc = (e == 0) ? Asrc0 : AsrcS;

  __shared__ ushort_t As[128 * 64];
  __shared__ ushort_t Bs[128 * 64];

  const int tid = threadIdx.x;
  const int wave = tid >> 6, lane = tid & 63;
  const int g = lane >> 4, lr = lane & 15;

  const ushort_t* Bbase = Btb + ((size_t)e * N + n0) * K;

  // Staging: 16 KB/tile = 16 wave-issues of 1KB; 4 per wave. Chunk index is
  // XOR-preswizzled at the global source (rule #21) so swizzled ds_reads see
  // linear data; LDS dest stays linear (global_load_lds requirement).
  const ushort_t* aSrcPtr[4];
  const ushort_t* bSrcPtr[4];
#pragma unroll
  for (int i = 0; i < 4; ++i) {
    int cidx = (wave * 4 + i) * 64 + lane;       // 16B chunk id, 0..1023
    int row = cidx >> 3;
    int ch = (cidx & 7) ^ (row & 7);             // pre-swizzled source chunk
    int mrow = m0 + row;
    int tok = (e == 0) ? mrow : list[mrow < cnt ? mrow : cnt - 1];
    aSrcPtr[i] = Asrc + (size_t)tok * K + ch * 8;
    bSrcPtr[i] = Bbase + (size_t)row * K + ch * 8;
  }

  f32x4 acc[4][4];
#pragma unroll
  for (int mi = 0; mi < 4; ++mi)
#pragma unroll
    for (int ni = 0; ni < 4; ++ni) acc[mi][ni] = (f32x4){0.f, 0.f, 0.f, 0.f};

  const int wm = wave >> 1, wn = wave & 1;
  const int swz = (lr & 7) << 4;

  for (int k0 = 0; k0 < K; k0 += 64) {
#pragma unroll
    for (int i = 0; i < 4; ++i)
      gl_lds16(aSrcPtr[i] + k0, &As[(wave * 4 + i) * 512]);
#pragma unroll
    for (int i = 0; i < 4; ++i)
      gl_lds16(bSrcPtr[i] + k0, &Bs[(wave * 4 + i) * 512]);
    __syncthreads();
#pragma unroll
    for (int kk = 0; kk < 2; ++kk) {
      bf16x8 af[4], bfv[4];
#pragma unroll
      for (int mi = 0; mi < 4; ++mi) {
        int row = wm * 64 + mi * 16 + lr;
        int off = row * 128 + ((kk * 64 + g * 16) ^ swz);
        af[mi] = *(const bf16x8*)((const char*)As + off);
      }
#pragma unroll
      for (int ni = 0; ni < 4; ++ni) {
        int row = wn * 64 + ni * 16 + lr;
        int off = row * 128 + ((kk * 64 + g * 16) ^ swz);
        bfv[ni] = *(const bf16x8*)((const char*)Bs + off);
      }
#pragma unroll
      for (int mi = 0; mi < 4; ++mi)
#pragma unroll
        for (int ni = 0; ni < 4; ++ni)
          acc[mi][ni] = __builtin_amdgcn_mfma_f32_16x16x32_bf16(
              af[mi], bfv[ni], acc[mi][ni], 0, 0, 0);
    }
    __syncthreads();
  }

  // Epilogue. C/D layout: col = lane&15, row = (lane>>4)*4 + reg  [m89].
#pragma unroll
  for (int mi = 0; mi < 4; ++mi) {
#pragma unroll
    for (int r = 0; r < 4; ++r) {
      const int mrow = m0 + wm * 64 + mi * 16 + g * 4 + r;
      if (mrow >= cnt) continue;
      const int tok = (e == 0) ? mrow : list[mrow];
#pragma unroll
      for (int ni = 0; ni < 4; ++ni) {
        const int col = n0 + wn * 64 + ni * 16 + lr;
        float v = acc[mi][ni][r] + bias[e * N + col];
        if constexpr (PASS1) {
          float gv = 0.5f * v * (1.0f + erff(v * 0.70710678118654752f));
          ushort_t* Dst = (e == 0) ? D0b : DSb;
          Dst[(size_t)tok * N + col] = f2bf(gv);
        } else {
          float* Dst = (e == 0) ? D0f : DSf;
          Dst[(size_t)tok * N + col] = v;
        }
      }
    }
  }
}

// ------------- final mix -----------------------------------------------------
__global__ __launch_bounds__(256) void combine_kernel(
    const float* __restrict__ Ocm, const float* __restrict__ Osel,
    const float* __restrict__ p, const int* __restrict__ routes,
    float* __restrict__ out) {
  const int idx = blockIdx.x * blockDim.x + threadIdx.x;  // one float4
  const int t = idx / (DM / 4);
  f32x4 cm = ((const f32x4*)Ocm)[idx];
  const int r = routes[t];
  f32x4 res;
  if (r == 0) {
    res = cm;
  } else {
    const float pe = p[t];
    f32x4 sl = ((const f32x4*)Osel)[idx];
    res = pe * sl + (1.0f - pe) * cm;
  }
  ((f32x4*)out)[idx] = res;
}

extern "C" void kernel_launch(void* const* d_in, const int* in_sizes, int n_in,
                              void* d_out, int out_size, void* d_ws,
                              size_t ws_size, hipStream_t stream) {
  const float* x  = (const float*)d_in[0];
  const float* Ws = (const float*)d_in[1];
  const float* bs = (const float*)d_in[2];
  const float* W1 = (const float*)d_in[3];
  const float* b1 = (const float*)d_in[4];
  const float* W2 = (const float*)d_in[5];
  const float* b2 = (const float*)d_in[6];
  float* out = (float*)d_out;
  char* ws = (char*)d_ws;

  // ws layout (~83.5 MB). Wtb is reused: W1^T for pass1, then W2^T for pass2.
  constexpr size_t XB_OFF  = 0;                              // 2048*768*2
  constexpr size_t WTB_OFF = XB_OFF + (size_t)T_TOK * DM * 2;          // 9*3072*768*2
  constexpr size_t H0_OFF  = WTB_OFF + (size_t)NE * DF * DM * 2;       // 2048*3072*2
  constexpr size_t HS_OFF  = H0_OFF + (size_t)T_TOK * DF * 2;
  constexpr size_t OC_OFF  = HS_OFF + (size_t)T_TOK * DF * 2;          // f32
  constexpr size_t OS_OFF  = OC_OFF + (size_t)T_TOK * DM * 4;
  constexpr size_t P_OFF   = OS_OFF + (size_t)T_TOK * DM * 4;
  constexpr size_t RT_OFF  = P_OFF + (size_t)T_TOK * 4;
  constexpr size_t CNT_OFF = RT_OFF + (size_t)T_TOK * 4;
  constexpr size_t LST_OFF = CNT_OFF + 64;

  ushort_t* xb   = (ushort_t*)(ws + XB_OFF);
  ushort_t* Wtb  = (ushort_t*)(ws + WTB_OFF);
  ushort_t* H0   = (ushort_t*)(ws + H0_OFF);
  ushort_t* Hsel = (ushort_t*)(ws + HS_OFF);
  float* Ocm     = (float*)(ws + OC_OFF);
  float* Osel    = (float*)(ws + OS_OFF);
  float* p       = (float*)(ws + P_OFF);
  int* routes    = (int*)(ws + RT_OFF);
  int* counts    = (int*)(ws + CNT_OFF);
  int* lists     = (int*)(ws + LST_OFF);

  hipMemsetAsync(counts, 0, 64, stream);
  route_kernel<<<T_TOK / 4, 256, 0, stream>>>(x, Ws, bs, xb, p, routes, counts,
                                              lists);
  // W1 (E,768,3072) -> Wtb (E,3072,768) bf16
  transpose_conv<<<dim3(DF / 32, DM / 32, NE), 256, 0, stream>>>(W1, Wtb, DM,
                                                                 DF);
  ffn_gemm<DM, DF, true><<<dim3(DF / 128, T_TOK / 128, NE), 256, 0, stream>>>(
      xb, xb, Wtb, b1, counts, lists, H0, Hsel, nullptr, nullptr);
  // W2 (E,3072,768) -> Wtb (E,768,3072) bf16
  transpose_conv<<<dim3(DM / 32, DF / 32, NE), 256, 0, stream>>>(W2, Wtb, DF,
                                                                 DM);
  ffn_gemm<DF, DM, false><<<dim3(DM / 128, T_TOK / 128, NE), 256, 0, stream>>>(
      H0, Hsel, Wtb, b2, counts, lists, nullptr, nullptr, Ocm, Osel);
  combine_kernel<<<(T_TOK * DM / 4) / 256, 256, 0, stream>>>(Ocm, Osel, p,
                                                             routes, out);
}